// Round 6
// baseline (634.395 us; speedup 1.0000x reference)
//
#include <hip/hip_runtime.h>

#define N_NODES 100000
#define N_EDGES 1250000
#define DIM 64

#define B_SHIFT 7
#define BUCKET_NODES 128
#define NBUCKETS ((N_NODES + BUCKET_NODES - 1) / BUCKET_NODES)   // 782
#define CAP 2560            // slots per bucket; mean load 1598, sd ~40
#define P_CHUNK 4096
#define P_THREADS 512
#define EDGES_PER_THREAD (P_CHUNK / P_THREADS)                   // 8
#define NBLK_P ((N_EDGES + P_CHUNK - 1) / P_CHUNK)               // 306
#define N_TILES (N_NODES / 16)                                   // 6250
#define GEMM_BLOCKS ((N_TILES + (P_THREADS / 64) - 1) / (P_THREADS / 64))  // 782
#define SG_THREADS 1024

typedef __attribute__((ext_vector_type(8))) short short8;    // 8 bf16 = 4 VGPR
typedef __attribute__((ext_vector_type(4))) float f32x4;

static __host__ __device__ inline size_t align256(size_t x) { return (x + 255) & ~(size_t)255; }

__device__ inline float bf16_to_f32(unsigned short u) {
  return __uint_as_float(((unsigned)u) << 16);
}
__device__ inline unsigned short f32_to_bf16(float f) {
  unsigned u = __float_as_uint(f);
  u += 0x7FFFu + ((u >> 16) & 1u);   // RNE
  return (unsigned short)(u >> 16);
}

// ---------------- Fused: [0, NBLK_P) direct-scatter partition | rest: MFMA GEMM ----------------
// R5 attribution: sort_gather was the real sink (34.8us/rep); fused here is ~20us timed
// (44us figures were rocprof replay inflation of atomic-heavy kernels). Keep this as-is.
__global__ __launch_bounds__(P_THREADS) void fused_gemm_partition(
    const float* __restrict__ x,
    const float* __restrict__ W1,
    const float* __restrict__ W2,
    unsigned short* __restrict__ y1b,
    unsigned short* __restrict__ y2b,
    const int* __restrict__ ei,
    int* __restrict__ gcursor,
    unsigned* __restrict__ pairs,
    int nTiles) {
  __shared__ int h[NBUCKETS];
  __shared__ int gb[NBUCKETS];
  __shared__ int cur[NBUCKETS];

  if (blockIdx.x < NBLK_P) {
    // ---------- partition: histogram -> global base -> direct scatter ----------
    const int nE = N_EDGES;
    int tid = threadIdx.x;
    int base = blockIdx.x * P_CHUNK;
    int end = min(base + P_CHUNK, nE);

    for (int i = tid; i < NBUCKETS; i += P_THREADS) h[i] = 0;
    __syncthreads();

    int dstv[EDGES_PER_THREAD], srcv[EDGES_PER_THREAD];
#pragma unroll
    for (int k = 0; k < EDGES_PER_THREAD; ++k) {
      int e = base + tid + k * P_THREADS;
      if (e < end) {
        dstv[k] = ei[nE + e];
        srcv[k] = ei[e];
      } else {
        dstv[k] = -1;
        srcv[k] = 0;
      }
    }
#pragma unroll
    for (int k = 0; k < EDGES_PER_THREAD; ++k)
      if (dstv[k] >= 0) atomicAdd(&h[dstv[k] >> B_SHIFT], 1);
    __syncthreads();

    for (int i = tid; i < NBUCKETS; i += P_THREADS) {
      int c = h[i];
      gb[i] = c ? atomicAdd(&gcursor[i], c) : 0;
      cur[i] = 0;
    }
    __syncthreads();

#pragma unroll
    for (int k = 0; k < EDGES_PER_THREAD; ++k) {
      if (dstv[k] < 0) continue;
      int b = dstv[k] >> B_SHIFT;
      int inb = atomicAdd(&cur[b], 1);
      int gpos = gb[b] + inb;
      if (gpos < CAP)
        pairs[(size_t)b * CAP + gpos] =
            (unsigned)srcv[k] | ((unsigned)(dstv[k] & (BUCKET_NODES - 1)) << 17);
    }
  } else {
    // ---------- GEMM: one wave = ONE 16-row x 64-col tile, both W's ----------
    // Layouts (verified learn_hip m89/m120): A[m][k]: m=lane&15, k=(lane>>4)*8+j;
    // B[k][n]: n=lane&15, same k; C/D: col=lane&15, row=(lane>>4)*4+reg.
    int lane = threadIdx.x & 63;
    int t = ((blockIdx.x - NBLK_P) * P_THREADS + (int)threadIdx.x) >> 6;
    if (t >= nTiles) return;
    int m = lane & 15;
    int q = lane >> 4;

    short8 wf[2][2][4];
#pragma unroll
    for (int w = 0; w < 2; ++w) {
      const float* W = w ? W2 : W1;
#pragma unroll
      for (int kh = 0; kh < 2; ++kh)
#pragma unroll
        for (int nt = 0; nt < 4; ++nt) {
          short8 f;
#pragma unroll
          for (int j = 0; j < 8; ++j) {
            int k = kh * 32 + q * 8 + j;
            f[j] = (short)f32_to_bf16(W[k * DIM + nt * 16 + m]);
          }
          wf[w][kh][nt] = f;
        }
    }

    int rowBase = t * 16;
    const float* xr = x + (size_t)(rowBase + m) * DIM + q * 8;

    short8 af[2];
#pragma unroll
    for (int kh = 0; kh < 2; ++kh) {
      float4 u0 = *(const float4*)(xr + kh * 32);
      float4 u1 = *(const float4*)(xr + kh * 32 + 4);
      short8 f;
      f[0] = (short)f32_to_bf16(u0.x);
      f[1] = (short)f32_to_bf16(u0.y);
      f[2] = (short)f32_to_bf16(u0.z);
      f[3] = (short)f32_to_bf16(u0.w);
      f[4] = (short)f32_to_bf16(u1.x);
      f[5] = (short)f32_to_bf16(u1.y);
      f[6] = (short)f32_to_bf16(u1.z);
      f[7] = (short)f32_to_bf16(u1.w);
      af[kh] = f;
    }

#pragma unroll
    for (int w = 0; w < 2; ++w) {
      unsigned short* Y = w ? y2b : y1b;
      f32x4 acc[4];
#pragma unroll
      for (int nt = 0; nt < 4; ++nt) {
        acc[nt] = (f32x4){0.f, 0.f, 0.f, 0.f};
        acc[nt] = __builtin_amdgcn_mfma_f32_16x16x32_bf16(af[0], wf[w][0][nt], acc[nt], 0, 0, 0);
        acc[nt] = __builtin_amdgcn_mfma_f32_16x16x32_bf16(af[1], wf[w][1][nt], acc[nt], 0, 0, 0);
      }
#pragma unroll
      for (int nt = 0; nt < 4; ++nt)
#pragma unroll
        for (int r = 0; r < 4; ++r)
          Y[(size_t)(rowBase + q * 4 + r) * DIM + nt * 16 + m] = f32_to_bf16(acc[nt][r]);
    }
  }
}

// ---------------- v6: edge-parallel gather + LDS f32 accumulate (replaces sort_gather) ----------------
// R5 showed sort_gather's serial per-node gather chains (2-4 loads in flight/wave against
// ~500cy LLC latency) cost 34.8us. Here each 16-lane group handles one edge: load the
// 128B y2b row, fire-and-forget ds_add_f32 into acc[128][64] (32KB LDS). No sort, no
// serial chains, no shuffle reduce; 64 row-loads in flight per block. Bank pattern
// (c16*4+j)%32 = 2-way = free (m136). FP-add order changes; prior versions already
// reordered (atomic placement) and passed absmax 0.0625.
__global__ __launch_bounds__(SG_THREADS) void accum_gather(
    const unsigned* __restrict__ pairs,
    const int* __restrict__ gcursor,
    const unsigned short* __restrict__ y1b,
    const unsigned short* __restrict__ y2b,
    float* __restrict__ out,
    int nNodesTotal) {
  __shared__ float acc[BUCKET_NODES * DIM];   // 32 KB

  int b = blockIdx.x;
  int n = min(gcursor[b], CAP);
  int tid = threadIdx.x;
  const unsigned* pb = pairs + (size_t)b * CAP;

  for (int i = tid; i < BUCKET_NODES * DIM; i += SG_THREADS) acc[i] = 0.f;
  __syncthreads();

  int g16 = tid >> 4;      // 64 edge slots in flight per block
  int c16 = tid & 15;      // ushort4 column within the row
  const ushort4* y2q = (const ushort4*)y2b;   // row stride = 16 ushort4

  for (int i = g16; i < n; i += SG_THREADS / 16) {
    unsigned w = pb[i];                        // 16 lanes same addr -> broadcast fetch
    int src = (int)(w & 0x1FFFFu);
    int dl  = (int)((w >> 17) & 127u);
    ushort4 u = y2q[(size_t)src * 16 + c16];
    float* a = &acc[dl * DIM + c16 * 4];
    atomicAdd(a + 0, bf16_to_f32(u.x));        // ds_add_f32, no return
    atomicAdd(a + 1, bf16_to_f32(u.y));
    atomicAdd(a + 2, bf16_to_f32(u.z));
    atomicAdd(a + 3, bf16_to_f32(u.w));
  }
  __syncthreads();

  // self part + relu + store
  int nodeBase = b << B_SHIFT;
  int numNodes = min(BUCKET_NODES, nNodesTotal - nodeBase);
  const ushort4* y1q = (const ushort4*)y1b;
  for (int idx = tid; idx < numNodes * 16; idx += SG_THREADS) {
    int ln = idx >> 4;
    int c = idx & 15;
    int node = nodeBase + ln;
    ushort4 s1v = y1q[(size_t)node * 16 + c];
    const float* a = &acc[ln * DIM + c * 4];
    float4 o;
    o.x = fmaxf(bf16_to_f32(s1v.x) + a[0], 0.0f);
    o.y = fmaxf(bf16_to_f32(s1v.y) + a[1], 0.0f);
    o.z = fmaxf(bf16_to_f32(s1v.z) + a[2], 0.0f);
    o.w = fmaxf(bf16_to_f32(s1v.w) + a[3], 0.0f);
    ((float4*)out)[(size_t)node * 16 + c] = o;
  }
}

// ---------------- Fallback path ----------------
__global__ __launch_bounds__(256) void gemm_simple(
    const float* __restrict__ x, const float* __restrict__ W1, const float* __restrict__ W2,
    float* __restrict__ y1, unsigned short* __restrict__ y2b, int n) {
  int row = blockIdx.x * blockDim.x + threadIdx.x;
  if (row >= n) return;
  float xv[DIM];
  const float4* xr = (const float4*)(x + (size_t)row * DIM);
#pragma unroll
  for (int i = 0; i < DIM / 4; ++i) {
    float4 t = xr[i];
    xv[4 * i] = t.x; xv[4 * i + 1] = t.y; xv[4 * i + 2] = t.z; xv[4 * i + 3] = t.w;
  }
#pragma unroll
  for (int m = 0; m < 2; ++m) {
    const float* W = (m == 0) ? W1 : W2;
#pragma unroll
    for (int cc = 0; cc < DIM; cc += 16) {
      float acc[16];
#pragma unroll
      for (int c2 = 0; c2 < 16; ++c2) acc[c2] = 0.0f;
      for (int k = 0; k < DIM; ++k) {
        float xk = xv[k];
        const float* wr = W + k * DIM + cc;
#pragma unroll
        for (int c2 = 0; c2 < 16; ++c2) acc[c2] = fmaf(xk, wr[c2], acc[c2]);
      }
      if (m == 0) {
        for (int c2 = 0; c2 < 16; ++c2) y1[(size_t)row * DIM + cc + c2] = acc[c2];
      } else {
        for (int c2 = 0; c2 < 16; ++c2) y2b[(size_t)row * DIM + cc + c2] = f32_to_bf16(acc[c2]);
      }
    }
  }
}

__global__ __launch_bounds__(256) void scatter_add(const int* __restrict__ ei,
                                                   const unsigned short* __restrict__ y2b,
                                                   float* __restrict__ out, int nE) {
  int gid = blockIdx.x * blockDim.x + threadIdx.x;
  int edge = gid >> 6;
  int lane = threadIdx.x & 63;
  if (edge >= nE) return;
  int src = __builtin_amdgcn_readfirstlane(ei[edge]);
  int dst = __builtin_amdgcn_readfirstlane(ei[nE + edge]);
  atomicAdd(&out[(size_t)dst * DIM + lane], bf16_to_f32(y2b[(size_t)src * DIM + lane]));
}

__global__ __launch_bounds__(256) void relu_inplace(float* __restrict__ out, int n4) {
  int i = blockIdx.x * blockDim.x + threadIdx.x;
  if (i >= n4) return;
  float4* p = (float4*)out;
  float4 v = p[i];
  v.x = fmaxf(v.x, 0.0f);
  v.y = fmaxf(v.y, 0.0f);
  v.z = fmaxf(v.z, 0.0f);
  v.w = fmaxf(v.w, 0.0f);
  p[i] = v;
}

extern "C" void kernel_launch(void* const* d_in, const int* in_sizes, int n_in,
                              void* d_out, int out_size, void* d_ws, size_t ws_size,
                              hipStream_t stream) {
  const float* x  = (const float*)d_in[0];
  const int*   ei = (const int*)d_in[1];
  const float* W1 = (const float*)d_in[2];
  const float* W2 = (const float*)d_in[3];
  float* out = (float*)d_out;

  char* ws = (char*)d_ws;
  size_t off = 0;
  unsigned short* y2b = (unsigned short*)(ws + off); off += align256((size_t)N_NODES * DIM * sizeof(unsigned short));
  unsigned short* y1b = (unsigned short*)(ws + off); off += align256((size_t)N_NODES * DIM * sizeof(unsigned short));
  int* gcursor = (int*)(ws + off);                   off += align256((size_t)NBUCKETS * sizeof(int));
  unsigned* pairs = (unsigned*)(ws + off);           off += align256((size_t)NBUCKETS * CAP * sizeof(unsigned));
  size_t required = off;

  if (ws_size >= required) {
    hipMemsetAsync(gcursor, 0, (size_t)NBUCKETS * sizeof(int), stream);
    fused_gemm_partition<<<NBLK_P + GEMM_BLOCKS, P_THREADS, 0, stream>>>(
        x, W1, W2, y1b, y2b, ei, gcursor, pairs, N_TILES);
    accum_gather<<<NBUCKETS, SG_THREADS, 0, stream>>>(pairs, gcursor, y1b, y2b, out, N_NODES);
  } else {
    {
      int blocks = (N_NODES + 255) / 256;
      gemm_simple<<<blocks, 256, 0, stream>>>(x, W1, W2, out, y2b, N_NODES);
    }
    {
      long long threads = (long long)N_EDGES * 64;
      int blocks = (int)((threads + 255) / 256);
      scatter_add<<<blocks, 256, 0, stream>>>(ei, y2b, out, N_EDGES);
    }
    {
      int n4 = N_NODES * DIM / 4;
      int blocks = (n4 + 255) / 256;
      relu_inplace<<<blocks, 256, 0, stream>>>(out, n4);
    }
  }
}

// Round 7
// 144.429 us; speedup vs baseline: 4.3924x; 4.3924x over previous
//
#include <hip/hip_runtime.h>

#define N_NODES 100000
#define N_EDGES 1250000
#define DIM 64

#define B_SHIFT 7
#define BUCKET_NODES 128
#define NBUCKETS ((N_NODES + BUCKET_NODES - 1) / BUCKET_NODES)   // 782
#define CAP 2560            // slots per bucket; mean load 1598, sd ~40
#define P_CHUNK 4096
#define P_THREADS 512
#define EDGES_PER_THREAD (P_CHUNK / P_THREADS)                   // 8
#define NBLK_P ((N_EDGES + P_CHUNK - 1) / P_CHUNK)               // 306
#define N_TILES (N_NODES / 16)                                   // 6250
#define GEMM_BLOCKS ((N_TILES + (P_THREADS / 64) - 1) / (P_THREADS / 64))  // 782
#define SG_THREADS 1024

typedef __attribute__((ext_vector_type(8))) short short8;    // 8 bf16 = 4 VGPR
typedef __attribute__((ext_vector_type(4))) float f32x4;

static __host__ __device__ inline size_t align256(size_t x) { return (x + 255) & ~(size_t)255; }

__device__ inline float bf16_to_f32(unsigned short u) {
  return __uint_as_float(((unsigned)u) << 16);
}
__device__ inline unsigned short f32_to_bf16(float f) {
  unsigned u = __float_as_uint(f);
  u += 0x7FFFu + ((u >> 16) & 1u);   // RNE
  return (unsigned short)(u >> 16);
}

// ---------------- Fused: [0, NBLK_P) direct-scatter partition | rest: MFMA GEMM ----------------
// (R4 version, best-measured config. R5 attribution: this kernel ~20us timed; the 44us
// rocprof figures were replay inflation of atomic-heavy kernels.)
__global__ __launch_bounds__(P_THREADS) void fused_gemm_partition(
    const float* __restrict__ x,
    const float* __restrict__ W1,
    const float* __restrict__ W2,
    unsigned short* __restrict__ y1b,
    unsigned short* __restrict__ y2b,
    const int* __restrict__ ei,
    int* __restrict__ gcursor,
    unsigned* __restrict__ pairs,
    int nTiles) {
  __shared__ int h[NBUCKETS];
  __shared__ int gb[NBUCKETS];
  __shared__ int cur[NBUCKETS];

  if (blockIdx.x < NBLK_P) {
    // ---------- partition: histogram -> global base -> direct scatter ----------
    const int nE = N_EDGES;
    int tid = threadIdx.x;
    int base = blockIdx.x * P_CHUNK;
    int end = min(base + P_CHUNK, nE);

    for (int i = tid; i < NBUCKETS; i += P_THREADS) h[i] = 0;
    __syncthreads();

    int dstv[EDGES_PER_THREAD], srcv[EDGES_PER_THREAD];
#pragma unroll
    for (int k = 0; k < EDGES_PER_THREAD; ++k) {
      int e = base + tid + k * P_THREADS;
      if (e < end) {
        dstv[k] = ei[nE + e];
        srcv[k] = ei[e];
      } else {
        dstv[k] = -1;
        srcv[k] = 0;
      }
    }
#pragma unroll
    for (int k = 0; k < EDGES_PER_THREAD; ++k)
      if (dstv[k] >= 0) atomicAdd(&h[dstv[k] >> B_SHIFT], 1);
    __syncthreads();

    for (int i = tid; i < NBUCKETS; i += P_THREADS) {
      int c = h[i];
      gb[i] = c ? atomicAdd(&gcursor[i], c) : 0;
      cur[i] = 0;
    }
    __syncthreads();

#pragma unroll
    for (int k = 0; k < EDGES_PER_THREAD; ++k) {
      if (dstv[k] < 0) continue;
      int b = dstv[k] >> B_SHIFT;
      int inb = atomicAdd(&cur[b], 1);
      int gpos = gb[b] + inb;
      if (gpos < CAP)
        pairs[(size_t)b * CAP + gpos] =
            (unsigned)srcv[k] | ((unsigned)(dstv[k] & (BUCKET_NODES - 1)) << 17);
    }
  } else {
    // ---------- GEMM: one wave = ONE 16-row x 64-col tile, both W's ----------
    // Layouts (verified learn_hip m89/m120): A[m][k]: m=lane&15, k=(lane>>4)*8+j;
    // B[k][n]: n=lane&15, same k; C/D: col=lane&15, row=(lane>>4)*4+reg.
    int lane = threadIdx.x & 63;
    int t = ((blockIdx.x - NBLK_P) * P_THREADS + (int)threadIdx.x) >> 6;
    if (t >= nTiles) return;
    int m = lane & 15;
    int q = lane >> 4;

    short8 wf[2][2][4];
#pragma unroll
    for (int w = 0; w < 2; ++w) {
      const float* W = w ? W2 : W1;
#pragma unroll
      for (int kh = 0; kh < 2; ++kh)
#pragma unroll
        for (int nt = 0; nt < 4; ++nt) {
          short8 f;
#pragma unroll
          for (int j = 0; j < 8; ++j) {
            int k = kh * 32 + q * 8 + j;
            f[j] = (short)f32_to_bf16(W[k * DIM + nt * 16 + m]);
          }
          wf[w][kh][nt] = f;
        }
    }

    int rowBase = t * 16;
    const float* xr = x + (size_t)(rowBase + m) * DIM + q * 8;

    short8 af[2];
#pragma unroll
    for (int kh = 0; kh < 2; ++kh) {
      float4 u0 = *(const float4*)(xr + kh * 32);
      float4 u1 = *(const float4*)(xr + kh * 32 + 4);
      short8 f;
      f[0] = (short)f32_to_bf16(u0.x);
      f[1] = (short)f32_to_bf16(u0.y);
      f[2] = (short)f32_to_bf16(u0.z);
      f[3] = (short)f32_to_bf16(u0.w);
      f[4] = (short)f32_to_bf16(u1.x);
      f[5] = (short)f32_to_bf16(u1.y);
      f[6] = (short)f32_to_bf16(u1.z);
      f[7] = (short)f32_to_bf16(u1.w);
      af[kh] = f;
    }

#pragma unroll
    for (int w = 0; w < 2; ++w) {
      unsigned short* Y = w ? y2b : y1b;
      f32x4 acc[4];
#pragma unroll
      for (int nt = 0; nt < 4; ++nt) {
        acc[nt] = (f32x4){0.f, 0.f, 0.f, 0.f};
        acc[nt] = __builtin_amdgcn_mfma_f32_16x16x32_bf16(af[0], wf[w][0][nt], acc[nt], 0, 0, 0);
        acc[nt] = __builtin_amdgcn_mfma_f32_16x16x32_bf16(af[1], wf[w][1][nt], acc[nt], 0, 0, 0);
      }
#pragma unroll
      for (int nt = 0; nt < 4; ++nt)
#pragma unroll
        for (int r = 0; r < 4; ++r)
          Y[(size_t)(rowBase + q * 4 + r) * DIM + nt * 16 + m] = f32_to_bf16(acc[nt][r]);
    }
  }
}

// ---------------- v7: per-bucket sort (LDS, unchanged) + group-per-node ILP gather ----------------
// R5: sort_gather = 34.8us, latency-bound (VALU 50%, HBM 34%): each wave walked its 8
// nodes SEQUENTIALLY -> ~24 dependent L2-latency rounds. R6: LDS fp atomics = disaster
// (530us, CAS-lowered). v7 keeps the deterministic reduce but restructures for ILP:
// one node per 16-lane group (4 nodes live per wave, 2 passes), per-node edge loop
// unrolled 4-wide with CLAMPED unconditional loads -> 4 independent 128B gathers in
// flight per group, no shuffle reduce (lane directly owns 4 output columns).
__global__ __launch_bounds__(SG_THREADS) void sort_gather(
    const unsigned* __restrict__ pairs,
    const int* __restrict__ gcursor,
    const unsigned short* __restrict__ y1b,
    const unsigned short* __restrict__ y2b,
    float* __restrict__ out,
    int nNodesTotal) {
  __shared__ unsigned buf[CAP];
  __shared__ unsigned sorted[CAP];
  __shared__ int cnt[BUCKET_NODES];
  __shared__ int scn[BUCKET_NODES];     // inclusive scan
  __shared__ int cur[BUCKET_NODES];     // placement cursor

  int b = blockIdx.x;
  int n = min(gcursor[b], CAP);
  int tid = threadIdx.x;
  const unsigned* pb = pairs + (size_t)b * CAP;

  if (tid < BUCKET_NODES) cnt[tid] = 0;
  __syncthreads();
  for (int i = tid; i < n; i += SG_THREADS) {
    unsigned w = pb[i];
    buf[i] = w;
    atomicAdd(&cnt[(w >> 17) & 127], 1);
  }
  __syncthreads();

  // wave-0 scan over 128 bins, 2 bins/lane
  if (tid < 64) {
    int b0 = tid * 2;
    int c0 = cnt[b0], c1 = cnt[b0 + 1];
    int s = c0 + c1;
#pragma unroll
    for (int off = 1; off < 64; off <<= 1) {
      int t = __shfl_up(s, off, 64);
      if (tid >= off) s += t;
    }
    scn[b0] = s - c1;
    scn[b0 + 1] = s;
    cur[b0] = s - c1 - c0;
    cur[b0 + 1] = s - c1;
  }
  __syncthreads();

  for (int i = tid; i < n; i += SG_THREADS) {
    unsigned w = buf[i];
    int l = (int)((w >> 17) & 127);
    int p = atomicAdd(&cur[l], 1);
    sorted[p] = w & 0x1FFFFu;
  }
  __syncthreads();

  // ---------- gather: 16-lane group owns one node; 4-wide clamped unroll ----------
  int lane = tid & 63;
  int wv = tid >> 6;                 // 0..15
  int g = lane >> 4;                 // node slot within wave (0..3)
  int c16 = lane & 15;               // ushort4 column (lane owns cols 4*c16..4*c16+3)
  const ushort4* y2q = (const ushort4*)y2b;   // row stride = 16 ushort4
  const ushort4* y1q = (const ushort4*)y1b;
  int nodeBase = b << B_SHIFT;
  int numNodes = min(BUCKET_NODES, nNodesTotal - nodeBase);

#pragma unroll
  for (int p = 0; p < 2; ++p) {
    int ln = wv * 8 + p * 4 + g;     // nodes 8*wv .. 8*wv+7 across 2 passes
    int deg = cnt[ln];               // group-uniform (same-address LDS broadcast)
    int begin = scn[ln] - deg;
    int end = begin + deg;

    float a0 = 0.f, a1 = 0.f, a2 = 0.f, a3 = 0.f;
    for (int e = begin; e < end; e += 4) {
      // clamped indices: all 4 loads always issue (4 in flight), tail masked on add
      int i1 = min(e + 1, end - 1);
      int i2 = min(e + 2, end - 1);
      int i3 = min(e + 3, end - 1);
      int s0 = (int)sorted[e];
      int s1 = (int)sorted[i1];
      int s2 = (int)sorted[i2];
      int s3 = (int)sorted[i3];
      ushort4 u0 = y2q[(size_t)s0 * 16 + c16];
      ushort4 u1 = y2q[(size_t)s1 * 16 + c16];
      ushort4 u2 = y2q[(size_t)s2 * 16 + c16];
      ushort4 u3 = y2q[(size_t)s3 * 16 + c16];
      a0 += bf16_to_f32(u0.x); a1 += bf16_to_f32(u0.y);
      a2 += bf16_to_f32(u0.z); a3 += bf16_to_f32(u0.w);
      if (e + 1 < end) {
        a0 += bf16_to_f32(u1.x); a1 += bf16_to_f32(u1.y);
        a2 += bf16_to_f32(u1.z); a3 += bf16_to_f32(u1.w);
      }
      if (e + 2 < end) {
        a0 += bf16_to_f32(u2.x); a1 += bf16_to_f32(u2.y);
        a2 += bf16_to_f32(u2.z); a3 += bf16_to_f32(u2.w);
      }
      if (e + 3 < end) {
        a0 += bf16_to_f32(u3.x); a1 += bf16_to_f32(u3.y);
        a2 += bf16_to_f32(u3.z); a3 += bf16_to_f32(u3.w);
      }
    }

    if (ln < numNodes) {
      int node = nodeBase + ln;
      ushort4 s1v = y1q[(size_t)node * 16 + c16];
      float4 o;
      o.x = fmaxf(bf16_to_f32(s1v.x) + a0, 0.0f);
      o.y = fmaxf(bf16_to_f32(s1v.y) + a1, 0.0f);
      o.z = fmaxf(bf16_to_f32(s1v.z) + a2, 0.0f);
      o.w = fmaxf(bf16_to_f32(s1v.w) + a3, 0.0f);
      ((float4*)out)[(size_t)node * 16 + c16] = o;
    }
  }
}

// ---------------- Fallback path ----------------
__global__ __launch_bounds__(256) void gemm_simple(
    const float* __restrict__ x, const float* __restrict__ W1, const float* __restrict__ W2,
    float* __restrict__ y1, unsigned short* __restrict__ y2b, int n) {
  int row = blockIdx.x * blockDim.x + threadIdx.x;
  if (row >= n) return;
  float xv[DIM];
  const float4* xr = (const float4*)(x + (size_t)row * DIM);
#pragma unroll
  for (int i = 0; i < DIM / 4; ++i) {
    float4 t = xr[i];
    xv[4 * i] = t.x; xv[4 * i + 1] = t.y; xv[4 * i + 2] = t.z; xv[4 * i + 3] = t.w;
  }
#pragma unroll
  for (int m = 0; m < 2; ++m) {
    const float* W = (m == 0) ? W1 : W2;
#pragma unroll
    for (int cc = 0; cc < DIM; cc += 16) {
      float acc[16];
#pragma unroll
      for (int c2 = 0; c2 < 16; ++c2) acc[c2] = 0.0f;
      for (int k = 0; k < DIM; ++k) {
        float xk = xv[k];
        const float* wr = W + k * DIM + cc;
#pragma unroll
        for (int c2 = 0; c2 < 16; ++c2) acc[c2] = fmaf(xk, wr[c2], acc[c2]);
      }
      if (m == 0) {
        for (int c2 = 0; c2 < 16; ++c2) y1[(size_t)row * DIM + cc + c2] = acc[c2];
      } else {
        for (int c2 = 0; c2 < 16; ++c2) y2b[(size_t)row * DIM + cc + c2] = f32_to_bf16(acc[c2]);
      }
    }
  }
}

__global__ __launch_bounds__(256) void scatter_add(const int* __restrict__ ei,
                                                   const unsigned short* __restrict__ y2b,
                                                   float* __restrict__ out, int nE) {
  int gid = blockIdx.x * blockDim.x + threadIdx.x;
  int edge = gid >> 6;
  int lane = threadIdx.x & 63;
  if (edge >= nE) return;
  int src = __builtin_amdgcn_readfirstlane(ei[edge]);
  int dst = __builtin_amdgcn_readfirstlane(ei[nE + edge]);
  atomicAdd(&out[(size_t)dst * DIM + lane], bf16_to_f32(y2b[(size_t)src * DIM + lane]));
}

__global__ __launch_bounds__(256) void relu_inplace(float* __restrict__ out, int n4) {
  int i = blockIdx.x * blockDim.x + threadIdx.x;
  if (i >= n4) return;
  float4* p = (float4*)out;
  float4 v = p[i];
  v.x = fmaxf(v.x, 0.0f);
  v.y = fmaxf(v.y, 0.0f);
  v.z = fmaxf(v.z, 0.0f);
  v.w = fmaxf(v.w, 0.0f);
  p[i] = v;
}

extern "C" void kernel_launch(void* const* d_in, const int* in_sizes, int n_in,
                              void* d_out, int out_size, void* d_ws, size_t ws_size,
                              hipStream_t stream) {
  const float* x  = (const float*)d_in[0];
  const int*   ei = (const int*)d_in[1];
  const float* W1 = (const float*)d_in[2];
  const float* W2 = (const float*)d_in[3];
  float* out = (float*)d_out;

  char* ws = (char*)d_ws;
  size_t off = 0;
  unsigned short* y2b = (unsigned short*)(ws + off); off += align256((size_t)N_NODES * DIM * sizeof(unsigned short));
  unsigned short* y1b = (unsigned short*)(ws + off); off += align256((size_t)N_NODES * DIM * sizeof(unsigned short));
  int* gcursor = (int*)(ws + off);                   off += align256((size_t)NBUCKETS * sizeof(int));
  unsigned* pairs = (unsigned*)(ws + off);           off += align256((size_t)NBUCKETS * CAP * sizeof(unsigned));
  size_t required = off;

  if (ws_size >= required) {
    hipMemsetAsync(gcursor, 0, (size_t)NBUCKETS * sizeof(int), stream);
    fused_gemm_partition<<<NBLK_P + GEMM_BLOCKS, P_THREADS, 0, stream>>>(
        x, W1, W2, y1b, y2b, ei, gcursor, pairs, N_TILES);
    sort_gather<<<NBUCKETS, SG_THREADS, 0, stream>>>(pairs, gcursor, y1b, y2b, out, N_NODES);
  } else {
    {
      int blocks = (N_NODES + 255) / 256;
      gemm_simple<<<blocks, 256, 0, stream>>>(x, W1, W2, out, y2b, N_NODES);
    }
    {
      long long threads = (long long)N_EDGES * 64;
      int blocks = (int)((threads + 255) / 256);
      scatter_add<<<blocks, 256, 0, stream>>>(ei, y2b, out, N_EDGES);
    }
    {
      int n4 = N_NODES * DIM / 4;
      int blocks = (n4 + 255) / 256;
      relu_inplace<<<blocks, 256, 0, stream>>>(out, n4);
    }
  }
}

// Round 8
// 143.610 us; speedup vs baseline: 4.4175x; 1.0057x over previous
//
#include <hip/hip_runtime.h>

#define N_NODES 100000
#define N_EDGES 1250000
#define DIM 64

#define B_SHIFT 7
#define BUCKET_NODES 128
#define NBUCKETS ((N_NODES + BUCKET_NODES - 1) / BUCKET_NODES)   // 782
#define CAP 2560            // slots per bucket; mean load 1598, sd ~40
#define P_CHUNK 4096
#define P_THREADS 512
#define EDGES_PER_THREAD (P_CHUNK / P_THREADS)                   // 8
#define NBLK_P ((N_EDGES + P_CHUNK - 1) / P_CHUNK)               // 306
#define N_TILES (N_NODES / 16)                                   // 6250
#define GEMM_BLOCKS ((N_TILES + (P_THREADS / 64) - 1) / (P_THREADS / 64))  // 782
#define SG_THREADS 512      // v8: 8 waves/block, ~12KB LDS -> 4 blocks/CU -> all 782
                            // buckets resident in ONE round (was 1.53 rounds at 1024 thr)

typedef __attribute__((ext_vector_type(8))) short short8;    // 8 bf16 = 4 VGPR
typedef __attribute__((ext_vector_type(4))) float f32x4;

static __host__ __device__ inline size_t align256(size_t x) { return (x + 255) & ~(size_t)255; }

__device__ inline float bf16_to_f32(unsigned short u) {
  return __uint_as_float(((unsigned)u) << 16);
}
__device__ inline unsigned short f32_to_bf16(float f) {
  unsigned u = __float_as_uint(f);
  u += 0x7FFFu + ((u >> 16) & 1u);   // RNE
  return (unsigned short)(u >> 16);
}

// ---------------- Fused: [0, NBLK_P) direct-scatter partition | rest: MFMA GEMM ----------------
// (unchanged from R7; R5 attribution: ~20us timed, not the bottleneck)
__global__ __launch_bounds__(P_THREADS) void fused_gemm_partition(
    const float* __restrict__ x,
    const float* __restrict__ W1,
    const float* __restrict__ W2,
    unsigned short* __restrict__ y1b,
    unsigned short* __restrict__ y2b,
    const int* __restrict__ ei,
    int* __restrict__ gcursor,
    unsigned* __restrict__ pairs,
    int nTiles) {
  __shared__ int h[NBUCKETS];
  __shared__ int gb[NBUCKETS];
  __shared__ int cur[NBUCKETS];

  if (blockIdx.x < NBLK_P) {
    const int nE = N_EDGES;
    int tid = threadIdx.x;
    int base = blockIdx.x * P_CHUNK;
    int end = min(base + P_CHUNK, nE);

    for (int i = tid; i < NBUCKETS; i += P_THREADS) h[i] = 0;
    __syncthreads();

    int dstv[EDGES_PER_THREAD], srcv[EDGES_PER_THREAD];
#pragma unroll
    for (int k = 0; k < EDGES_PER_THREAD; ++k) {
      int e = base + tid + k * P_THREADS;
      if (e < end) {
        dstv[k] = ei[nE + e];
        srcv[k] = ei[e];
      } else {
        dstv[k] = -1;
        srcv[k] = 0;
      }
    }
#pragma unroll
    for (int k = 0; k < EDGES_PER_THREAD; ++k)
      if (dstv[k] >= 0) atomicAdd(&h[dstv[k] >> B_SHIFT], 1);
    __syncthreads();

    for (int i = tid; i < NBUCKETS; i += P_THREADS) {
      int c = h[i];
      gb[i] = c ? atomicAdd(&gcursor[i], c) : 0;
      cur[i] = 0;
    }
    __syncthreads();

#pragma unroll
    for (int k = 0; k < EDGES_PER_THREAD; ++k) {
      if (dstv[k] < 0) continue;
      int b = dstv[k] >> B_SHIFT;
      int inb = atomicAdd(&cur[b], 1);
      int gpos = gb[b] + inb;
      if (gpos < CAP)
        pairs[(size_t)b * CAP + gpos] =
            (unsigned)srcv[k] | ((unsigned)(dstv[k] & (BUCKET_NODES - 1)) << 17);
    }
  } else {
    // ---------- GEMM: one wave = ONE 16-row x 64-col tile, both W's ----------
    // Layouts (verified learn_hip m89/m120): A[m][k]: m=lane&15, k=(lane>>4)*8+j;
    // B[k][n]: n=lane&15, same k; C/D: col=lane&15, row=(lane>>4)*4+reg.
    int lane = threadIdx.x & 63;
    int t = ((blockIdx.x - NBLK_P) * P_THREADS + (int)threadIdx.x) >> 6;
    if (t >= nTiles) return;
    int m = lane & 15;
    int q = lane >> 4;

    short8 wf[2][2][4];
#pragma unroll
    for (int w = 0; w < 2; ++w) {
      const float* W = w ? W2 : W1;
#pragma unroll
      for (int kh = 0; kh < 2; ++kh)
#pragma unroll
        for (int nt = 0; nt < 4; ++nt) {
          short8 f;
#pragma unroll
          for (int j = 0; j < 8; ++j) {
            int k = kh * 32 + q * 8 + j;
            f[j] = (short)f32_to_bf16(W[k * DIM + nt * 16 + m]);
          }
          wf[w][kh][nt] = f;
        }
    }

    int rowBase = t * 16;
    const float* xr = x + (size_t)(rowBase + m) * DIM + q * 8;

    short8 af[2];
#pragma unroll
    for (int kh = 0; kh < 2; ++kh) {
      float4 u0 = *(const float4*)(xr + kh * 32);
      float4 u1 = *(const float4*)(xr + kh * 32 + 4);
      short8 f;
      f[0] = (short)f32_to_bf16(u0.x);
      f[1] = (short)f32_to_bf16(u0.y);
      f[2] = (short)f32_to_bf16(u0.z);
      f[3] = (short)f32_to_bf16(u0.w);
      f[4] = (short)f32_to_bf16(u1.x);
      f[5] = (short)f32_to_bf16(u1.y);
      f[6] = (short)f32_to_bf16(u1.z);
      f[7] = (short)f32_to_bf16(u1.w);
      af[kh] = f;
    }

#pragma unroll
    for (int w = 0; w < 2; ++w) {
      unsigned short* Y = w ? y2b : y1b;
      f32x4 acc[4];
#pragma unroll
      for (int nt = 0; nt < 4; ++nt) {
        acc[nt] = (f32x4){0.f, 0.f, 0.f, 0.f};
        acc[nt] = __builtin_amdgcn_mfma_f32_16x16x32_bf16(af[0], wf[w][0][nt], acc[nt], 0, 0, 0);
        acc[nt] = __builtin_amdgcn_mfma_f32_16x16x32_bf16(af[1], wf[w][1][nt], acc[nt], 0, 0, 0);
      }
#pragma unroll
      for (int nt = 0; nt < 4; ++nt)
#pragma unroll
        for (int r = 0; r < 4; ++r)
          Y[(size_t)(rowBase + q * 4 + r) * DIM + nt * 16 + m] = f32_to_bf16(acc[nt][r]);
    }
  }
}

// ---------------- v8: sort (no buf staging) + work-queue balanced ILP gather ----------------
// R7 neutrality killed the latency-chain model. Remaining mechanisms: (a) 1024-thr
// blocks -> 2/CU -> 1.53 scheduling rounds for 782 buckets (2nd round 53% idle);
// (b) static node->group binding -> wave runtime = max(deg of 4 groups) ~ 17 vs 12.5
// mean. v8: 512 threads + ~12KB LDS -> 4 blocks/CU -> all buckets in one round;
// dynamic LDS queue balances degree skew. Gather body = v7's 4-wide clamped unroll.
__global__ __launch_bounds__(SG_THREADS) void sort_gather(
    const unsigned* __restrict__ pairs,
    const int* __restrict__ gcursor,
    const unsigned short* __restrict__ y1b,
    const unsigned short* __restrict__ y2b,
    float* __restrict__ out,
    int nNodesTotal) {
  __shared__ unsigned sorted[CAP];      // 10 KB
  __shared__ int cnt[BUCKET_NODES];
  __shared__ int scn[BUCKET_NODES];     // inclusive scan
  __shared__ int cur[BUCKET_NODES];     // placement cursor
  __shared__ int qhead;                 // dynamic node queue

  int b = blockIdx.x;
  int n = min(gcursor[b], CAP);
  int tid = threadIdx.x;
  const unsigned* pb = pairs + (size_t)b * CAP;

  if (tid < BUCKET_NODES) cnt[tid] = 0;
  if (tid == 0) qhead = SG_THREADS / 16;   // 32 groups take nodes 0..31 statically first
  __syncthreads();
  for (int i = tid; i < n; i += SG_THREADS)
    atomicAdd(&cnt[(pb[i] >> 17) & 127], 1);
  __syncthreads();

  // wave-0 scan over 128 bins, 2 bins/lane
  if (tid < 64) {
    int b0 = tid * 2;
    int c0 = cnt[b0], c1 = cnt[b0 + 1];
    int s = c0 + c1;
#pragma unroll
    for (int off = 1; off < 64; off <<= 1) {
      int t = __shfl_up(s, off, 64);
      if (tid >= off) s += t;
    }
    scn[b0] = s - c1;
    scn[b0 + 1] = s;
    cur[b0] = s - c1 - c0;
    cur[b0 + 1] = s - c1;
  }
  __syncthreads();

  for (int i = tid; i < n; i += SG_THREADS) {
    unsigned w = pb[i];                  // L2 re-read (6.4KB) instead of 10KB LDS buf
    int l = (int)((w >> 17) & 127);
    int p = atomicAdd(&cur[l], 1);
    sorted[p] = w & 0x1FFFFu;
  }
  __syncthreads();

  // ---------- gather: 16-lane group per node, dynamic queue, 4-wide clamped unroll ----------
  int lane = tid & 63;
  int g = lane >> 4;                 // group within wave (0..3)
  int c16 = lane & 15;               // ushort4 column (lane owns cols 4*c16..4*c16+3)
  const ushort4* y2q = (const ushort4*)y2b;   // row stride = 16 ushort4
  const ushort4* y1q = (const ushort4*)y1b;
  int nodeBase = b << B_SHIFT;
  int numNodes = min(BUCKET_NODES, nNodesTotal - nodeBase);

  int ln = (tid >> 4);               // initial static assignment: group id 0..31
  while (ln < BUCKET_NODES) {
    int deg = cnt[ln];               // group-uniform (same-address LDS broadcast)
    int begin = scn[ln] - deg;
    int end = begin + deg;

    float a0 = 0.f, a1 = 0.f, a2 = 0.f, a3 = 0.f;
    for (int e = begin; e < end; e += 4) {
      // clamped indices: all 4 loads always issue (4 in flight), tail masked on add
      int i1 = min(e + 1, end - 1);
      int i2 = min(e + 2, end - 1);
      int i3 = min(e + 3, end - 1);
      int s0 = (int)sorted[e];
      int s1 = (int)sorted[i1];
      int s2 = (int)sorted[i2];
      int s3 = (int)sorted[i3];
      ushort4 u0 = y2q[(size_t)s0 * 16 + c16];
      ushort4 u1 = y2q[(size_t)s1 * 16 + c16];
      ushort4 u2 = y2q[(size_t)s2 * 16 + c16];
      ushort4 u3 = y2q[(size_t)s3 * 16 + c16];
      a0 += bf16_to_f32(u0.x); a1 += bf16_to_f32(u0.y);
      a2 += bf16_to_f32(u0.z); a3 += bf16_to_f32(u0.w);
      if (e + 1 < end) {
        a0 += bf16_to_f32(u1.x); a1 += bf16_to_f32(u1.y);
        a2 += bf16_to_f32(u1.z); a3 += bf16_to_f32(u1.w);
      }
      if (e + 2 < end) {
        a0 += bf16_to_f32(u2.x); a1 += bf16_to_f32(u2.y);
        a2 += bf16_to_f32(u2.z); a3 += bf16_to_f32(u2.w);
      }
      if (e + 3 < end) {
        a0 += bf16_to_f32(u3.x); a1 += bf16_to_f32(u3.y);
        a2 += bf16_to_f32(u3.z); a3 += bf16_to_f32(u3.w);
      }
    }

    if (ln < numNodes) {
      int node = nodeBase + ln;
      ushort4 s1v = y1q[(size_t)node * 16 + c16];
      float4 o;
      o.x = fmaxf(bf16_to_f32(s1v.x) + a0, 0.0f);
      o.y = fmaxf(bf16_to_f32(s1v.y) + a1, 0.0f);
      o.z = fmaxf(bf16_to_f32(s1v.z) + a2, 0.0f);
      o.w = fmaxf(bf16_to_f32(s1v.w) + a3, 0.0f);
      ((float4*)out)[(size_t)node * 16 + c16] = o;
    }

    // grab next node: group leader atomics, broadcast within group via shfl
    int nx;
    if (c16 == 0) nx = atomicAdd(&qhead, 1);
    nx = __shfl(nx, g * 16, 64);
    ln = nx;
  }
}

// ---------------- Fallback path ----------------
__global__ __launch_bounds__(256) void gemm_simple(
    const float* __restrict__ x, const float* __restrict__ W1, const float* __restrict__ W2,
    float* __restrict__ y1, unsigned short* __restrict__ y2b, int n) {
  int row = blockIdx.x * blockDim.x + threadIdx.x;
  if (row >= n) return;
  float xv[DIM];
  const float4* xr = (const float4*)(x + (size_t)row * DIM);
#pragma unroll
  for (int i = 0; i < DIM / 4; ++i) {
    float4 t = xr[i];
    xv[4 * i] = t.x; xv[4 * i + 1] = t.y; xv[4 * i + 2] = t.z; xv[4 * i + 3] = t.w;
  }
#pragma unroll
  for (int m = 0; m < 2; ++m) {
    const float* W = (m == 0) ? W1 : W2;
#pragma unroll
    for (int cc = 0; cc < DIM; cc += 16) {
      float acc[16];
#pragma unroll
      for (int c2 = 0; c2 < 16; ++c2) acc[c2] = 0.0f;
      for (int k = 0; k < DIM; ++k) {
        float xk = xv[k];
        const float* wr = W + k * DIM + cc;
#pragma unroll
        for (int c2 = 0; c2 < 16; ++c2) acc[c2] = fmaf(xk, wr[c2], acc[c2]);
      }
      if (m == 0) {
        for (int c2 = 0; c2 < 16; ++c2) y1[(size_t)row * DIM + cc + c2] = acc[c2];
      } else {
        for (int c2 = 0; c2 < 16; ++c2) y2b[(size_t)row * DIM + cc + c2] = f32_to_bf16(acc[c2]);
      }
    }
  }
}

__global__ __launch_bounds__(256) void scatter_add(const int* __restrict__ ei,
                                                   const unsigned short* __restrict__ y2b,
                                                   float* __restrict__ out, int nE) {
  int gid = blockIdx.x * blockDim.x + threadIdx.x;
  int edge = gid >> 6;
  int lane = threadIdx.x & 63;
  if (edge >= nE) return;
  int src = __builtin_amdgcn_readfirstlane(ei[edge]);
  int dst = __builtin_amdgcn_readfirstlane(ei[nE + edge]);
  atomicAdd(&out[(size_t)dst * DIM + lane], bf16_to_f32(y2b[(size_t)src * DIM + lane]));
}

__global__ __launch_bounds__(256) void relu_inplace(float* __restrict__ out, int n4) {
  int i = blockIdx.x * blockDim.x + threadIdx.x;
  if (i >= n4) return;
  float4* p = (float4*)out;
  float4 v = p[i];
  v.x = fmaxf(v.x, 0.0f);
  v.y = fmaxf(v.y, 0.0f);
  v.z = fmaxf(v.z, 0.0f);
  v.w = fmaxf(v.w, 0.0f);
  p[i] = v;
}

extern "C" void kernel_launch(void* const* d_in, const int* in_sizes, int n_in,
                              void* d_out, int out_size, void* d_ws, size_t ws_size,
                              hipStream_t stream) {
  const float* x  = (const float*)d_in[0];
  const int*   ei = (const int*)d_in[1];
  const float* W1 = (const float*)d_in[2];
  const float* W2 = (const float*)d_in[3];
  float* out = (float*)d_out;

  char* ws = (char*)d_ws;
  size_t off = 0;
  unsigned short* y2b = (unsigned short*)(ws + off); off += align256((size_t)N_NODES * DIM * sizeof(unsigned short));
  unsigned short* y1b = (unsigned short*)(ws + off); off += align256((size_t)N_NODES * DIM * sizeof(unsigned short));
  int* gcursor = (int*)(ws + off);                   off += align256((size_t)NBUCKETS * sizeof(int));
  unsigned* pairs = (unsigned*)(ws + off);           off += align256((size_t)NBUCKETS * CAP * sizeof(unsigned));
  size_t required = off;

  if (ws_size >= required) {
    hipMemsetAsync(gcursor, 0, (size_t)NBUCKETS * sizeof(int), stream);
    fused_gemm_partition<<<NBLK_P + GEMM_BLOCKS, P_THREADS, 0, stream>>>(
        x, W1, W2, y1b, y2b, ei, gcursor, pairs, N_TILES);
    sort_gather<<<NBUCKETS, SG_THREADS, 0, stream>>>(pairs, gcursor, y1b, y2b, out, N_NODES);
  } else {
    {
      int blocks = (N_NODES + 255) / 256;
      gemm_simple<<<blocks, 256, 0, stream>>>(x, W1, W2, out, y2b, N_NODES);
    }
    {
      long long threads = (long long)N_EDGES * 64;
      int blocks = (int)((threads + 255) / 256);
      scatter_add<<<blocks, 256, 0, stream>>>(ei, y2b, out, N_EDGES);
    }
    {
      int n4 = N_NODES * DIM / 4;
      int blocks = (n4 + 255) / 256;
      relu_inplace<<<blocks, 256, 0, stream>>>(out, n4);
    }
  }
}

// Round 9
// 136.634 us; speedup vs baseline: 4.6430x; 1.0511x over previous
//
#include <hip/hip_runtime.h>

#define N_NODES 100000
#define N_EDGES 1250000
#define DIM 64

#define B_SHIFT 7
#define BUCKET_NODES 128
#define NBUCKETS ((N_NODES + BUCKET_NODES - 1) / BUCKET_NODES)   // 782
#define CAP 2560            // slots per bucket; mean load 1598, sd ~40
#define PHASES 4
#define BINS (PHASES * BUCKET_NODES)                             // 512
#define P_CHUNK 4096
#define P_THREADS 512
#define EDGES_PER_THREAD (P_CHUNK / P_THREADS)                   // 8
#define NBLK_P ((N_EDGES + P_CHUNK - 1) / P_CHUNK)               // 306
#define N_TILES (N_NODES / 16)                                   // 6250
#define GEMM_BLOCKS ((N_TILES + (P_THREADS / 64) - 1) / (P_THREADS / 64))  // 782
#define SG_THREADS 512

typedef __attribute__((ext_vector_type(8))) short short8;    // 8 bf16 = 4 VGPR
typedef __attribute__((ext_vector_type(4))) float f32x4;

static __host__ __device__ inline size_t align256(size_t x) { return (x + 255) & ~(size_t)255; }

__device__ inline float bf16_to_f32(unsigned short u) {
  return __uint_as_float(((unsigned)u) << 16);
}
__device__ inline float bf16lo_to_f32(unsigned w) {   // low 16 bits = bf16
  return __uint_as_float(w << 16);
}
__device__ inline float bf16hi_to_f32(unsigned w) {   // high 16 bits = bf16
  return __uint_as_float(w & 0xFFFF0000u);
}
__device__ inline unsigned short f32_to_bf16(float f) {
  unsigned u = __float_as_uint(f);
  u += 0x7FFFu + ((u >> 16) & 1u);   // RNE
  return (unsigned short)(u >> 16);
}

// ---------------- Fused: [0, NBLK_P) direct-scatter partition | rest: MFMA GEMM ----------------
// (unchanged from R8; R5 attribution: GEMM ~8us = memory floor, partition ~11us)
__global__ __launch_bounds__(P_THREADS) void fused_gemm_partition(
    const float* __restrict__ x,
    const float* __restrict__ W1,
    const float* __restrict__ W2,
    unsigned short* __restrict__ y1b,
    unsigned short* __restrict__ y2b,
    const int* __restrict__ ei,
    int* __restrict__ gcursor,
    unsigned* __restrict__ pairs,
    int nTiles) {
  __shared__ int h[NBUCKETS];
  __shared__ int gb[NBUCKETS];
  __shared__ int cur[NBUCKETS];

  if (blockIdx.x < NBLK_P) {
    const int nE = N_EDGES;
    int tid = threadIdx.x;
    int base = blockIdx.x * P_CHUNK;
    int end = min(base + P_CHUNK, nE);

    for (int i = tid; i < NBUCKETS; i += P_THREADS) h[i] = 0;
    __syncthreads();

    int dstv[EDGES_PER_THREAD], srcv[EDGES_PER_THREAD];
#pragma unroll
    for (int k = 0; k < EDGES_PER_THREAD; ++k) {
      int e = base + tid + k * P_THREADS;
      if (e < end) {
        dstv[k] = ei[nE + e];
        srcv[k] = ei[e];
      } else {
        dstv[k] = -1;
        srcv[k] = 0;
      }
    }
#pragma unroll
    for (int k = 0; k < EDGES_PER_THREAD; ++k)
      if (dstv[k] >= 0) atomicAdd(&h[dstv[k] >> B_SHIFT], 1);
    __syncthreads();

    for (int i = tid; i < NBUCKETS; i += P_THREADS) {
      int c = h[i];
      gb[i] = c ? atomicAdd(&gcursor[i], c) : 0;
      cur[i] = 0;
    }
    __syncthreads();

#pragma unroll
    for (int k = 0; k < EDGES_PER_THREAD; ++k) {
      if (dstv[k] < 0) continue;
      int b = dstv[k] >> B_SHIFT;
      int inb = atomicAdd(&cur[b], 1);
      int gpos = gb[b] + inb;
      if (gpos < CAP)
        pairs[(size_t)b * CAP + gpos] =
            (unsigned)srcv[k] | ((unsigned)(dstv[k] & (BUCKET_NODES - 1)) << 17);
    }
  } else {
    // ---------- GEMM: one wave = ONE 16-row x 64-col tile, both W's ----------
    // Layouts (verified learn_hip m89/m120): A[m][k]: m=lane&15, k=(lane>>4)*8+j;
    // B[k][n]: n=lane&15, same k; C/D: col=lane&15, row=(lane>>4)*4+reg.
    int lane = threadIdx.x & 63;
    int t = ((blockIdx.x - NBLK_P) * P_THREADS + (int)threadIdx.x) >> 6;
    if (t >= nTiles) return;
    int m = lane & 15;
    int q = lane >> 4;

    short8 wf[2][2][4];
#pragma unroll
    for (int w = 0; w < 2; ++w) {
      const float* W = w ? W2 : W1;
#pragma unroll
      for (int kh = 0; kh < 2; ++kh)
#pragma unroll
        for (int nt = 0; nt < 4; ++nt) {
          short8 f;
#pragma unroll
          for (int j = 0; j < 8; ++j) {
            int k = kh * 32 + q * 8 + j;
            f[j] = (short)f32_to_bf16(W[k * DIM + nt * 16 + m]);
          }
          wf[w][kh][nt] = f;
        }
    }

    int rowBase = t * 16;
    const float* xr = x + (size_t)(rowBase + m) * DIM + q * 8;

    short8 af[2];
#pragma unroll
    for (int kh = 0; kh < 2; ++kh) {
      float4 u0 = *(const float4*)(xr + kh * 32);
      float4 u1 = *(const float4*)(xr + kh * 32 + 4);
      short8 f;
      f[0] = (short)f32_to_bf16(u0.x);
      f[1] = (short)f32_to_bf16(u0.y);
      f[2] = (short)f32_to_bf16(u0.z);
      f[3] = (short)f32_to_bf16(u0.w);
      f[4] = (short)f32_to_bf16(u1.x);
      f[5] = (short)f32_to_bf16(u1.y);
      f[6] = (short)f32_to_bf16(u1.z);
      f[7] = (short)f32_to_bf16(u1.w);
      af[kh] = f;
    }

#pragma unroll
    for (int w = 0; w < 2; ++w) {
      unsigned short* Y = w ? y2b : y1b;
      f32x4 acc[4];
#pragma unroll
      for (int nt = 0; nt < 4; ++nt) {
        acc[nt] = (f32x4){0.f, 0.f, 0.f, 0.f};
        acc[nt] = __builtin_amdgcn_mfma_f32_16x16x32_bf16(af[0], wf[w][0][nt], acc[nt], 0, 0, 0);
        acc[nt] = __builtin_amdgcn_mfma_f32_16x16x32_bf16(af[1], wf[w][1][nt], acc[nt], 0, 0, 0);
      }
#pragma unroll
      for (int nt = 0; nt < 4; ++nt)
#pragma unroll
        for (int r = 0; r < 4; ++r)
          Y[(size_t)(rowBase + q * 4 + r) * DIM + nt * 16 + m] = f32_to_bf16(acc[nt][r]);
    }
  }
}

// ---------------- v9: 512-bin (src-phase, dst-local) sort + phase-swept L2-local gather ----------------
// R7/R8 exonerated latency chains, scheduling rounds, degree skew. Remaining mechanism:
// y2b (12.8MB) > 4MiB per-XCD L2 -> the 160MB random row-gather is LLC-served at
// ~4.6 TB/s effective. v9 sorts each bucket's edges by (phase = src/25600, dst_local):
// all blocks sweep phase 0..3 in rough lockstep, so the live src working set is
// 3.27MB <= L2/XCD and repeat touches become L2 hits. Gather: 8-lane groups, whole-row
// int4 loads (half the VMEM+LDS instrs of ushort4/16-lane), static 2 nodes/group with
// register accumulators held across phases.
__global__ __launch_bounds__(SG_THREADS) void sort_gather(
    const unsigned* __restrict__ pairs,
    const int* __restrict__ gcursor,
    const unsigned short* __restrict__ y1b,
    const unsigned short* __restrict__ y2b,
    float* __restrict__ out,
    int nNodesTotal) {
  __shared__ unsigned sorted[CAP];      // 10 KB (src only)
  __shared__ int cnt[BINS];             // 2 KB
  __shared__ int scn[BINS];             // inclusive scan, 2 KB
  __shared__ int cur[BINS];             // placement cursor, 2 KB

  int b = blockIdx.x;
  int n = min(gcursor[b], CAP);
  int tid = threadIdx.x;
  const unsigned* pb = pairs + (size_t)b * CAP;

  for (int i = tid; i < BINS; i += SG_THREADS) cnt[i] = 0;
  __syncthreads();
  for (int i = tid; i < n; i += SG_THREADS) {
    unsigned w = pb[i];
    unsigned src = w & 0x1FFFFu;
    int key = (int)(((src * 5243u) >> 27) << 7) | (int)((w >> 17) & 127u);
    atomicAdd(&cnt[key], 1);
  }
  __syncthreads();

  // wave-0 scan over 512 bins, 8 bins/lane
  if (tid < 64) {
    int k0 = tid * 8;
    int v[8];
    int lsum = 0;
#pragma unroll
    for (int j = 0; j < 8; ++j) { v[j] = cnt[k0 + j]; lsum += v[j]; }
    int s = lsum;
#pragma unroll
    for (int off = 1; off < 64; off <<= 1) {
      int t = __shfl_up(s, off, 64);
      if (tid >= off) s += t;
    }
    int run = s - lsum;
#pragma unroll
    for (int j = 0; j < 8; ++j) {
      cur[k0 + j] = run;
      run += v[j];
      scn[k0 + j] = run;
    }
  }
  __syncthreads();

  for (int i = tid; i < n; i += SG_THREADS) {
    unsigned w = pb[i];                  // L2 re-read instead of LDS buf
    unsigned src = w & 0x1FFFFu;
    int key = (int)(((src * 5243u) >> 27) << 7) | (int)((w >> 17) & 127u);
    int p = atomicAdd(&cur[key], 1);
    sorted[p] = src;
  }
  __syncthreads();

  // ---------- gather: 8-lane group, 2 static nodes/group, phase-major sweep ----------
  int gid = tid >> 3;                // 0..63 groups
  int c8 = tid & 7;                  // int4 column (lane owns cols 8*c8 .. 8*c8+7)
  const int4* y2q = (const int4*)y2b;   // row = 8 int4 (128B)
  const int4* y1q = (const int4*)y1b;
  int nodeBase = b << B_SHIFT;
  int numNodes = min(BUCKET_NODES, nNodesTotal - nodeBase);

  float acc[2][8];
#pragma unroll
  for (int nn = 0; nn < 2; ++nn)
#pragma unroll
    for (int j = 0; j < 8; ++j) acc[nn][j] = 0.f;

  for (int p = 0; p < PHASES; ++p) {
#pragma unroll
    for (int nn = 0; nn < 2; ++nn) {
      int ln = gid * 2 + nn;
      int k = (p << 7) | ln;
      int end = scn[k];
      int e = end - cnt[k];
      for (; e + 1 < end; e += 2) {
        int s0 = (int)sorted[e];
        int s1 = (int)sorted[e + 1];
        int4 v0 = y2q[(size_t)s0 * 8 + c8];
        int4 v1 = y2q[(size_t)s1 * 8 + c8];
#pragma unroll
        for (int j = 0; j < 4; ++j) {
          unsigned w0 = (unsigned)v0[j];
          unsigned w1 = (unsigned)v1[j];
          acc[nn][2 * j]     += bf16lo_to_f32(w0) + bf16lo_to_f32(w1);
          acc[nn][2 * j + 1] += bf16hi_to_f32(w0) + bf16hi_to_f32(w1);
        }
      }
      if (e < end) {
        int s0 = (int)sorted[e];
        int4 v0 = y2q[(size_t)s0 * 8 + c8];
#pragma unroll
        for (int j = 0; j < 4; ++j) {
          unsigned w0 = (unsigned)v0[j];
          acc[nn][2 * j]     += bf16lo_to_f32(w0);
          acc[nn][2 * j + 1] += bf16hi_to_f32(w0);
        }
      }
    }
  }

  // self part + relu + store: lane owns cols [8*c8, 8*c8+8) of its 2 nodes
#pragma unroll
  for (int nn = 0; nn < 2; ++nn) {
    int ln = gid * 2 + nn;
    if (ln < numNodes) {
      int node = nodeBase + ln;
      int4 s1v = y1q[(size_t)node * 8 + c8];
      float4 o0, o1;
      unsigned w0 = (unsigned)s1v[0], w1 = (unsigned)s1v[1];
      unsigned w2 = (unsigned)s1v[2], w3 = (unsigned)s1v[3];
      o0.x = fmaxf(bf16lo_to_f32(w0) + acc[nn][0], 0.0f);
      o0.y = fmaxf(bf16hi_to_f32(w0) + acc[nn][1], 0.0f);
      o0.z = fmaxf(bf16lo_to_f32(w1) + acc[nn][2], 0.0f);
      o0.w = fmaxf(bf16hi_to_f32(w1) + acc[nn][3], 0.0f);
      o1.x = fmaxf(bf16lo_to_f32(w2) + acc[nn][4], 0.0f);
      o1.y = fmaxf(bf16hi_to_f32(w2) + acc[nn][5], 0.0f);
      o1.z = fmaxf(bf16lo_to_f32(w3) + acc[nn][6], 0.0f);
      o1.w = fmaxf(bf16hi_to_f32(w3) + acc[nn][7], 0.0f);
      float4* orow = (float4*)(out + (size_t)node * DIM + c8 * 8);
      orow[0] = o0;
      orow[1] = o1;
    }
  }
}

// ---------------- Fallback path ----------------
__global__ __launch_bounds__(256) void gemm_simple(
    const float* __restrict__ x, const float* __restrict__ W1, const float* __restrict__ W2,
    float* __restrict__ y1, unsigned short* __restrict__ y2b, int n) {
  int row = blockIdx.x * blockDim.x + threadIdx.x;
  if (row >= n) return;
  float xv[DIM];
  const float4* xr = (const float4*)(x + (size_t)row * DIM);
#pragma unroll
  for (int i = 0; i < DIM / 4; ++i) {
    float4 t = xr[i];
    xv[4 * i] = t.x; xv[4 * i + 1] = t.y; xv[4 * i + 2] = t.z; xv[4 * i + 3] = t.w;
  }
#pragma unroll
  for (int m = 0; m < 2; ++m) {
    const float* W = (m == 0) ? W1 : W2;
#pragma unroll
    for (int cc = 0; cc < DIM; cc += 16) {
      float acc[16];
#pragma unroll
      for (int c2 = 0; c2 < 16; ++c2) acc[c2] = 0.0f;
      for (int k = 0; k < DIM; ++k) {
        float xk = xv[k];
        const float* wr = W + k * DIM + cc;
#pragma unroll
        for (int c2 = 0; c2 < 16; ++c2) acc[c2] = fmaf(xk, wr[c2], acc[c2]);
      }
      if (m == 0) {
        for (int c2 = 0; c2 < 16; ++c2) y1[(size_t)row * DIM + cc + c2] = acc[c2];
      } else {
        for (int c2 = 0; c2 < 16; ++c2) y2b[(size_t)row * DIM + cc + c2] = f32_to_bf16(acc[c2]);
      }
    }
  }
}

__global__ __launch_bounds__(256) void scatter_add(const int* __restrict__ ei,
                                                   const unsigned short* __restrict__ y2b,
                                                   float* __restrict__ out, int nE) {
  int gid = blockIdx.x * blockDim.x + threadIdx.x;
  int edge = gid >> 6;
  int lane = threadIdx.x & 63;
  if (edge >= nE) return;
  int src = __builtin_amdgcn_readfirstlane(ei[edge]);
  int dst = __builtin_amdgcn_readfirstlane(ei[nE + edge]);
  atomicAdd(&out[(size_t)dst * DIM + lane], bf16_to_f32(y2b[(size_t)src * DIM + lane]));
}

__global__ __launch_bounds__(256) void relu_inplace(float* __restrict__ out, int n4) {
  int i = blockIdx.x * blockDim.x + threadIdx.x;
  if (i >= n4) return;
  float4* p = (float4*)out;
  float4 v = p[i];
  v.x = fmaxf(v.x, 0.0f);
  v.y = fmaxf(v.y, 0.0f);
  v.z = fmaxf(v.z, 0.0f);
  v.w = fmaxf(v.w, 0.0f);
  p[i] = v;
}

extern "C" void kernel_launch(void* const* d_in, const int* in_sizes, int n_in,
                              void* d_out, int out_size, void* d_ws, size_t ws_size,
                              hipStream_t stream) {
  const float* x  = (const float*)d_in[0];
  const int*   ei = (const int*)d_in[1];
  const float* W1 = (const float*)d_in[2];
  const float* W2 = (const float*)d_in[3];
  float* out = (float*)d_out;

  char* ws = (char*)d_ws;
  size_t off = 0;
  unsigned short* y2b = (unsigned short*)(ws + off); off += align256((size_t)N_NODES * DIM * sizeof(unsigned short));
  unsigned short* y1b = (unsigned short*)(ws + off); off += align256((size_t)N_NODES * DIM * sizeof(unsigned short));
  int* gcursor = (int*)(ws + off);                   off += align256((size_t)NBUCKETS * sizeof(int));
  unsigned* pairs = (unsigned*)(ws + off);           off += align256((size_t)NBUCKETS * CAP * sizeof(unsigned));
  size_t required = off;

  if (ws_size >= required) {
    hipMemsetAsync(gcursor, 0, (size_t)NBUCKETS * sizeof(int), stream);
    fused_gemm_partition<<<NBLK_P + GEMM_BLOCKS, P_THREADS, 0, stream>>>(
        x, W1, W2, y1b, y2b, ei, gcursor, pairs, N_TILES);
    sort_gather<<<NBUCKETS, SG_THREADS, 0, stream>>>(pairs, gcursor, y1b, y2b, out, N_NODES);
  } else {
    {
      int blocks = (N_NODES + 255) / 256;
      gemm_simple<<<blocks, 256, 0, stream>>>(x, W1, W2, out, y2b, N_NODES);
    }
    {
      long long threads = (long long)N_EDGES * 64;
      int blocks = (int)((threads + 255) / 256);
      scatter_add<<<blocks, 256, 0, stream>>>(ei, y2b, out, N_EDGES);
    }
    {
      int n4 = N_NODES * DIM / 4;
      int blocks = (n4 + 255) / 256;
      relu_inplace<<<blocks, 256, 0, stream>>>(out, n4);
    }
  }
}